// Round 5
// baseline (1642.691 us; speedup 1.0000x reference)
//
#include <hip/hip_runtime.h>
#include <hip/hip_bf16.h>
#include <stdint.h>

// Problem constants
#define M_ROWS 32768
#define N_CODES 8192
#define K_DIM 256
#define NSLICE 64            // N_CODES / BN
#define MARGIN 0.25f         // coarse-key uncertainty window (2B), >20 sigma

// Coarse GEMM tile config (R2's proven structure: 128x128, BK=32)
#define BM 128
#define BN 128
#define BKT 32
#define GN 8                 // N-blocks per swizzle panel (L2 locality)

typedef _Float16 half8 __attribute__((ext_vector_type(8)));
typedef _Float16 h4v __attribute__((ext_vector_type(4)));
typedef float f4v __attribute__((ext_vector_type(4)));
typedef float f32x4 __attribute__((ext_vector_type(4)));
typedef __attribute__((address_space(3))) void lds_void;
typedef const __attribute__((address_space(1))) void gbl_cvoid;

struct Part { double d; long long c; };   // 16 B

// Monotone map: fp32 bits -> uint32 preserving < order (handles sign)
__device__ __forceinline__ unsigned long long pack_key(float d, unsigned col) {
    unsigned u = __float_as_uint(d);
    u = (u & 0x80000000u) ? ~u : (u | 0x80000000u);
    return ((unsigned long long)u << 32) | (unsigned long long)col;
}
__device__ __forceinline__ float unpack_key(unsigned long long k) {
    unsigned m = (unsigned)(k >> 32);
    unsigned u = (m & 0x80000000u) ? (m & 0x7fffffffu) : ~m;
    return __uint_as_float(u);
}
// 2-min pair merge: (b1,b2) <- two smallest of {b1,b2,o1,o2}
__device__ __forceinline__ void merge2(unsigned long long& b1, unsigned long long& b2,
                                       unsigned long long o1, unsigned long long o2) {
    unsigned long long n1 = b1 < o1 ? b1 : o1;
    unsigned long long hi = b1 < o1 ? o1 : b1;
    unsigned long long l2 = b2 < o2 ? b2 : o2;
    b2 = hi < l2 ? hi : l2;
    b1 = n1;
}

// ---------------- prep: z -> f16 (elementwise, grid-stride) -----------------
__global__ __launch_bounds__(256) void prep_zh(const float* __restrict__ z,
                                               _Float16* __restrict__ Aq) {
    int tid = blockIdx.x * 256 + threadIdx.x;
    const f4v* z4 = (const f4v*)z;
    #pragma unroll 1
    for (int i = tid; i < M_ROWS * (K_DIM / 4); i += 1024 * 256) {
        f4v v = z4[i];
        h4v h;
        #pragma unroll
        for (int j = 0; j < 4; ++j) h[j] = (_Float16)v[j];
        *(h4v*)&Aq[(size_t)i * 4] = h;
    }
}

// ---------------- prep: codebook -> f16 + esq (fp32) ------------------------
__global__ __launch_bounds__(256) void prep_beh(const float* __restrict__ cb,
                                                _Float16* __restrict__ Bq,
                                                float* __restrict__ esq) {
    int wave = threadIdx.x >> 6, lane = threadIdx.x & 63;
    int row = blockIdx.x * 4 + wave;                 // grid = 2048
    f4v v = *(const f4v*)(cb + (size_t)row * K_DIM + lane * 4);
    h4v h;
    float sq = 0.f;
    #pragma unroll
    for (int j = 0; j < 4; ++j) {
        h[j] = (_Float16)v[j];
        sq += v[j] * v[j];
    }
    *(h4v*)&Bq[(size_t)row * K_DIM + lane * 4] = h;
    #pragma unroll
    for (int m = 32; m; m >>= 1) sq += __shfl_xor(sq, m);
    if (lane == 0) esq[row] = sq;
}

// ---------------- coarse GEMM + fused 2-min argmin --------------------------
// key = esq - 2*(zh.eh)   (zsq dropped: row-constant)
__global__ __launch_bounds__(256) void coarse_gemm(
        const _Float16* __restrict__ Aq, const _Float16* __restrict__ Bq,
        const float* __restrict__ esq, ulonglong2* __restrict__ slices) {
    __shared__ __align__(16) _Float16 As[BM * BKT];  // 8 KB
    __shared__ __align__(16) _Float16 Bs[BN * BKT];  // 8 KB
    __shared__ ulonglong2 red[BM][2];                // 4 KB

    int bid = blockIdx.x;
    int bm = (bid / GN) % (M_ROWS / BM);
    int bn = (bid / (GN * (M_ROWS / BM))) * GN + (bid % GN);
    int m0 = bm * BM, n0 = bn * BN;

    int t = threadIdx.x;
    int lane = t & 63, wave = t >> 6;
    int quad = lane >> 4, l15 = lane & 15;
    int wm = (wave & 1) * 64, wn = (wave >> 1) * 64;

    f32x4 acc[4][4] = {};

    const _Float16* Ag = Aq + (size_t)m0 * K_DIM;
    const _Float16* Bg = Bq + (size_t)n0 * K_DIM;

    // stage 128 rows x 32 f16 (4x16B chunks per 64B row), stride 256 f16
    auto stage = [&](const _Float16* gbase, _Float16* lds) {
        #pragma unroll
        for (int i = 0; i < 2; ++i) {
            int c = t + i * 256;                     // chunk id 0..511
            int row = c >> 2, seg = c & 3;
            const _Float16* gp = gbase + (size_t)row * K_DIM + seg * 8;
            __builtin_amdgcn_global_load_lds((gbl_cvoid*)gp,
                                             (lds_void*)(lds + (size_t)c * 8),
                                             16, 0, 0);
        }
    };

    auto compute = [&]() {
        half8 af[4], bf[4];
        #pragma unroll
        for (int i = 0; i < 4; ++i) {
            af[i] = *(const half8*)&As[(wm + i * 16 + l15) * BKT + quad * 8];
            bf[i] = *(const half8*)&Bs[(wn + i * 16 + l15) * BKT + quad * 8];
        }
        #pragma unroll
        for (int mi = 0; mi < 4; ++mi)
            #pragma unroll
            for (int ni = 0; ni < 4; ++ni)
                acc[mi][ni] = __builtin_amdgcn_mfma_f32_16x16x32_f16(
                    af[mi], bf[ni], acc[mi][ni], 0, 0, 0);
    };

    #pragma unroll 1
    for (int kt = 0; kt < 8; ++kt) {
        __syncthreads();
        stage(Ag + kt * BKT, As);
        stage(Bg + kt * BKT, Bs);
        __syncthreads();
        compute();
    }

    // Epilogue: 2-smallest of key = fmaf(-2, acc, esq) per row over this slice
    float es[4];
    #pragma unroll
    for (int ni = 0; ni < 4; ++ni)
        es[ni] = esq[n0 + wn + ni * 16 + l15];

    #pragma unroll
    for (int mi = 0; mi < 4; ++mi) {
        #pragma unroll
        for (int r = 0; r < 4; ++r) {
            unsigned long long b1 = ~0ULL, b2 = ~0ULL;
            #pragma unroll
            for (int ni = 0; ni < 4; ++ni) {
                unsigned gCol = (unsigned)(n0 + wn + ni * 16 + l15);
                float key = fmaf(-2.0f, acc[mi][ni][r], es[ni]);
                unsigned long long p = pack_key(key, gCol);
                if (p < b1) { b2 = b1; b1 = p; }
                else if (p < b2) b2 = p;
            }
            #pragma unroll
            for (int m = 1; m < 16; m <<= 1) {
                unsigned long long o1 =
                    (unsigned long long)__shfl_xor((long long)b1, m);
                unsigned long long o2 =
                    (unsigned long long)__shfl_xor((long long)b2, m);
                merge2(b1, b2, o1, o2);
            }
            if (l15 == 0) {
                int rowl = wm + mi * 16 + quad * 4 + r;
                red[rowl][wave >> 1] = make_ulonglong2(b1, b2);
            }
        }
    }
    __syncthreads();
    if (t < BM) {
        ulonglong2 a = red[t][0], b = red[t][1];
        unsigned long long b1 = a.x, b2 = a.y;
        merge2(b1, b2, b.x, b.y);
        slices[(size_t)(m0 + t) * NSLICE + bn] = make_ulonglong2(b1, b2);
    }
}

// ---------------- merge slices -> bestidx + ambiguity flag ------------------
__global__ __launch_bounds__(256) void merge_slices(
        const ulonglong2* __restrict__ slices,
        int* __restrict__ bestidx, int* __restrict__ flags) {
    int wave = threadIdx.x >> 6, lane = threadIdx.x & 63;
    int row = blockIdx.x * 4 + wave;                 // grid = 8192
    ulonglong2 p = slices[(size_t)row * NSLICE + lane];
    unsigned long long b1 = p.x, b2 = p.y;
    #pragma unroll
    for (int m = 1; m < 64; m <<= 1) {
        unsigned long long o1 = (unsigned long long)__shfl_xor((long long)b1, m);
        unsigned long long o2 = (unsigned long long)__shfl_xor((long long)b2, m);
        merge2(b1, b2, o1, o2);
    }
    if (lane == 0) {
        bestidx[row] = (int)(unsigned)(b1 & 0xFFFFFFFFULL);
        flags[row] = (unpack_key(b2) - unpack_key(b1) <= MARGIN) ? 1 : 0;
    }
}

// ---------------- refine flagged rows: exact fp64 distance ------------------
// grid (8 code-chunks, 32 row-groups); block 256. Chunk = 1024 codes.
__global__ __launch_bounds__(256) void refine(const float* __restrict__ z,
                                              const float* __restrict__ cb,
                                              const int* __restrict__ flags,
                                              Part* __restrict__ part) {
    int cc = blockIdx.x, g = blockIdx.y;
    __shared__ int list[1024];
    __shared__ int cnt;
    __shared__ float zrow[K_DIM];
    __shared__ double wd[4];
    __shared__ int wc[4];
    int t = threadIdx.x;
    if (t == 0) cnt = 0;
    __syncthreads();
    for (int r = t; r < 1024; r += 256)
        if (flags[g * 1024 + r]) { int p = atomicAdd(&cnt, 1); list[p] = r; }
    __syncthreads();
    int n = cnt;
    #pragma unroll 1
    for (int li = 0; li < n; ++li) {
        int row = g * 1024 + list[li];
        __syncthreads();                             // protect zrow/wd reuse
        zrow[t] = z[(size_t)row * K_DIM + t];
        __syncthreads();
        double bd = 1e300; int bc = 0x7fffffff;
        #pragma unroll 1
        for (int j = 0; j < 4; ++j) {
            int code = cc * 1024 + j * 256 + t;
            const f4v* e4 = (const f4v*)(cb + (size_t)code * K_DIM);
            double s0 = 0, s1 = 0, s2 = 0, s3 = 0;
            #pragma unroll 4
            for (int k4 = 0; k4 < 64; ++k4) {
                f4v e = e4[k4];
                f4v zz = *(const f4v*)&zrow[k4 * 4];
                float d0 = zz[0] - e[0], d1 = zz[1] - e[1];
                float d2 = zz[2] - e[2], d3 = zz[3] - e[3];
                s0 = fma((double)d0, (double)d0, s0);
                s1 = fma((double)d1, (double)d1, s1);
                s2 = fma((double)d2, (double)d2, s2);
                s3 = fma((double)d3, (double)d3, s3);
            }
            double s = (s0 + s1) + (s2 + s3);
            if (s < bd || (s == bd && code < bc)) { bd = s; bc = code; }
        }
        #pragma unroll
        for (int m = 1; m < 64; m <<= 1) {
            double od = __shfl_xor(bd, m);
            int oc = __shfl_xor(bc, m);
            if (od < bd || (od == bd && oc < bc)) { bd = od; bc = oc; }
        }
        if ((t & 63) == 0) { wd[t >> 6] = bd; wc[t >> 6] = bc; }
        __syncthreads();
        if (t == 0) {
            #pragma unroll
            for (int w = 1; w < 4; ++w)
                if (wd[w] < bd || (wd[w] == bd && wc[w] < bc)) { bd = wd[w]; bc = wc[w]; }
            part[(size_t)row * 8 + cc] = Part{bd, (long long)bc};
        }
    }
}

// ---------------- final select for flagged rows -----------------------------
__global__ __launch_bounds__(256) void final_select(const int* __restrict__ flags,
                                                    const Part* __restrict__ part,
                                                    int* __restrict__ bestidx) {
    int row = blockIdx.x * 256 + threadIdx.x;        // grid = 128
    if (row < M_ROWS && flags[row]) {
        double bd = 1e300; long long bc = 0x7fffffff;
        #pragma unroll
        for (int c = 0; c < 8; ++c) {
            Part p = part[(size_t)row * 8 + c];
            if (p.d < bd || (p.d == bd && p.c < bc)) { bd = p.d; bc = p.c; }
        }
        bestidx[row] = (int)bc;
    }
}

// ---------------- ws-light fallback (only if ws too small) ------------------
__global__ __launch_bounds__(256) void vq_bruteforce(const float* __restrict__ z,
                                                     const float* __restrict__ cb,
                                                     float* __restrict__ out_idx) {
    __shared__ float As[128 * 16];
    __shared__ float Bs[128 * 16];
    int t = threadIdx.x;
    int tx = t & 15, ty = t >> 4;
    int r0 = blockIdx.x * 128;
    unsigned long long best[8];
    #pragma unroll
    for (int j = 0; j < 8; ++j) best[j] = ~0ULL;

    for (int n0 = 0; n0 < N_CODES; n0 += 128) {
        float acc[8][8] = {};
        for (int k0 = 0; k0 < K_DIM; k0 += 16) {
            __syncthreads();
            int row = t >> 1, c8 = (t & 1) * 8;
            #pragma unroll
            for (int j = 0; j < 8; ++j)
                As[row * 16 + c8 + j] = z[(size_t)(r0 + row) * K_DIM + k0 + c8 + j];
            #pragma unroll
            for (int j = 0; j < 8; ++j)
                Bs[row * 16 + c8 + j] = cb[(size_t)(n0 + row) * K_DIM + k0 + c8 + j];
            __syncthreads();
            #pragma unroll
            for (int k = 0; k < 16; ++k) {
                float a[8], b[8];
                #pragma unroll
                for (int j = 0; j < 8; ++j) a[j] = As[(ty * 8 + j) * 16 + k];
                #pragma unroll
                for (int j = 0; j < 8; ++j) b[j] = Bs[(tx * 8 + j) * 16 + k];
                #pragma unroll
                for (int i = 0; i < 8; ++i)
                    #pragma unroll
                    for (int j = 0; j < 8; ++j) {
                        float d = a[i] - b[j];
                        acc[i][j] += d * d;
                    }
            }
        }
        #pragma unroll
        for (int i = 0; i < 8; ++i) {
            unsigned long long bv = ~0ULL;
            #pragma unroll
            for (int j = 0; j < 8; ++j) {
                unsigned long long p =
                    pack_key(acc[i][j], (unsigned)(n0 + tx * 8 + j));
                bv = (p < bv) ? p : bv;
            }
            #pragma unroll
            for (int m = 1; m < 16; m <<= 1) {
                unsigned long long o =
                    (unsigned long long)__shfl_xor((long long)bv, m);
                bv = (o < bv) ? o : bv;
            }
            if (tx == 0 && bv < best[i]) best[i] = bv;
        }
    }
    if (tx == 0) {
        #pragma unroll
        for (int i = 0; i < 8; ++i)
            out_idx[r0 + ty * 8 + i] =
                (float)(unsigned)(best[i] & 0xFFFFFFFFULL);
    }
}

// ---------------- finalize: gather, straight-through out, loss sum ----------
__global__ __launch_bounds__(256) void finalize(const float* __restrict__ z,
                                                const float* __restrict__ cb,
                                                const int* __restrict__ bestidx,
                                                float* __restrict__ out,
                                                double* __restrict__ accum,
                                                int use_int) {
    int wave = threadIdx.x >> 6, lane = threadIdx.x & 63;
    float* out_idx = out + (size_t)M_ROWS * K_DIM;
    float se = 0.f;
    #pragma unroll 1
    for (int row = blockIdx.x * 4 + wave; row < M_ROWS; row += 1024 * 4) {
        int idx = use_int ? bestidx[row] : (int)out_idx[row];
        f4v zv = *(const f4v*)(z  + (size_t)row * K_DIM + lane * 4);
        f4v qv = *(const f4v*)(cb + (size_t)idx * K_DIM + lane * 4);
        f4v ov;
        #pragma unroll
        for (int j = 0; j < 4; ++j) {
            float d = qv[j] - zv[j];                 // ref: z_q - z_e
            ov[j] = zv[j] + d;                       // ref: z_e + (z_q - z_e)
            se += d * d;
        }
        *(f4v*)(out + (size_t)row * K_DIM + lane * 4) = ov;
        if (lane == 0) out_idx[row] = (float)idx;
    }
    #pragma unroll
    for (int m = 32; m; m >>= 1) se += __shfl_xor(se, m);
    __shared__ float part[4];
    if (lane == 0) part[wave] = se;
    __syncthreads();
    if (threadIdx.x == 0)
        atomicAdd(accum, (double)((part[0] + part[1]) + (part[2] + part[3])));
}

__global__ void write_loss(const double* __restrict__ accum,
                           float* __restrict__ out) {
    // vq_loss = codebook_loss + 0.25*commitment_loss = 1.25 * mean(diff^2)
    out[(size_t)M_ROWS * K_DIM + M_ROWS] =
        (float)(1.25 * (*accum / (double)((size_t)M_ROWS * K_DIM)));
}

// ---------------- launch ----------------------------------------------------
extern "C" void kernel_launch(void* const* d_in, const int* in_sizes, int n_in,
                              void* d_out, int out_size, void* d_ws, size_t ws_size,
                              hipStream_t stream) {
    const float* z  = (const float*)d_in[0];
    const float* cb = (const float*)d_in[1];
    float* out = (float*)d_out;
    float* out_idx = out + (size_t)M_ROWS * K_DIM;

    size_t offA  = 0;                                             // Aq 16 MB
    size_t offBq = offA + (size_t)M_ROWS * K_DIM * 2;             // Bq 4 MB
    size_t offE  = offBq + (size_t)N_CODES * K_DIM * 2;           // esq 32 KB
    size_t offS  = offE + (size_t)N_CODES * 4;                    // slices 32 MB
    size_t offBI = offS + (size_t)M_ROWS * NSLICE * 16;           // bestidx 128 KB
    size_t offF  = offBI + (size_t)M_ROWS * 4;                    // flags 128 KB
    size_t offP  = offF + (size_t)M_ROWS * 4;                     // part 4 MB
    size_t offAcc = offP + (size_t)M_ROWS * 8 * sizeof(Part);
    size_t need  = offAcc + 16;

    if (ws_size >= need) {
        _Float16* Aq = (_Float16*)((char*)d_ws + offA);
        _Float16* Bq = (_Float16*)((char*)d_ws + offBq);
        float* esq   = (float*)((char*)d_ws + offE);
        ulonglong2* slices = (ulonglong2*)((char*)d_ws + offS);
        int* bestidx = (int*)((char*)d_ws + offBI);
        int* flags   = (int*)((char*)d_ws + offF);
        Part* part   = (Part*)((char*)d_ws + offP);
        double* accum = (double*)((char*)d_ws + offAcc);

        hipMemsetAsync((char*)d_ws + offAcc, 0, sizeof(double), stream);

        prep_zh<<<1024, 256, 0, stream>>>(z, Aq);
        prep_beh<<<N_CODES / 4, 256, 0, stream>>>(cb, Bq, esq);
        coarse_gemm<<<(M_ROWS / BM) * (N_CODES / BN), 256, 0, stream>>>(
            Aq, Bq, esq, slices);
        merge_slices<<<M_ROWS / 4, 256, 0, stream>>>(slices, bestidx, flags);
        refine<<<dim3(8, 32), 256, 0, stream>>>(z, cb, flags, part);
        final_select<<<M_ROWS / 256, 256, 0, stream>>>(flags, part, bestidx);
        finalize<<<1024, 256, 0, stream>>>(z, cb, bestidx, out, accum, 1);
        write_loss<<<1, 1, 0, stream>>>(accum, out);
    } else {
        double* accum = (double*)d_ws;
        hipMemsetAsync(d_ws, 0, sizeof(double), stream);
        vq_bruteforce<<<M_ROWS / 128, 256, 0, stream>>>(z, cb, out_idx);
        finalize<<<1024, 256, 0, stream>>>(z, cb, nullptr, out, accum, 0);
        write_loss<<<1, 1, 0, stream>>>(accum, out);
    }
}

// Round 6
// 477.445 us; speedup vs baseline: 3.4406x; 3.4406x over previous
//
#include <hip/hip_runtime.h>
#include <hip/hip_bf16.h>
#include <stdint.h>

// Problem constants
#define M_ROWS 32768
#define N_CODES 8192
#define K_DIM 256
#define NSLICE 64            // N_CODES / BN
#define MARGIN 0.25f         // coarse-key uncertainty window (2E), ~40 sigma
#define MAXCAND 1280

// Coarse GEMM tile config (R2's proven structure: 128x128, BK=32)
#define BM 128
#define BN 128
#define BKT 32
#define GN 8                 // N-blocks per swizzle panel (L2 locality)

typedef _Float16 half8 __attribute__((ext_vector_type(8)));
typedef _Float16 h4v __attribute__((ext_vector_type(4)));
typedef float f4v __attribute__((ext_vector_type(4)));
typedef float f32x4 __attribute__((ext_vector_type(4)));
typedef __attribute__((address_space(3))) void lds_void;
typedef const __attribute__((address_space(1))) void gbl_cvoid;

// Monotone map: fp32 bits -> uint32 preserving < order (handles sign)
__device__ __forceinline__ unsigned long long pack_key(float d, unsigned col) {
    unsigned u = __float_as_uint(d);
    u = (u & 0x80000000u) ? ~u : (u | 0x80000000u);
    return ((unsigned long long)u << 32) | (unsigned long long)col;
}
__device__ __forceinline__ float unpack_key(unsigned long long k) {
    unsigned m = (unsigned)(k >> 32);
    unsigned u = (m & 0x80000000u) ? (m & 0x7fffffffu) : ~m;
    return __uint_as_float(u);
}
// 2-min pair merge: (b1,b2) <- two smallest of {b1,b2,o1,o2}
__device__ __forceinline__ void merge2(unsigned long long& b1, unsigned long long& b2,
                                       unsigned long long o1, unsigned long long o2) {
    unsigned long long n1 = b1 < o1 ? b1 : o1;
    unsigned long long hi = b1 < o1 ? o1 : b1;
    unsigned long long l2 = b2 < o2 ? b2 : o2;
    b2 = hi < l2 ? hi : l2;
    b1 = n1;
}

// ---------------- prep: z -> f16 (elementwise, grid-stride) -----------------
__global__ __launch_bounds__(256) void prep_zh(const float* __restrict__ z,
                                               _Float16* __restrict__ Aq) {
    int tid = blockIdx.x * 256 + threadIdx.x;
    const f4v* z4 = (const f4v*)z;
    #pragma unroll 1
    for (int i = tid; i < M_ROWS * (K_DIM / 4); i += 1024 * 256) {
        f4v v = z4[i];
        h4v h;
        #pragma unroll
        for (int j = 0; j < 4; ++j) h[j] = (_Float16)v[j];
        *(h4v*)&Aq[(size_t)i * 4] = h;
    }
}

// ---------------- prep: codebook -> f16 + esq (fp32) ------------------------
__global__ __launch_bounds__(256) void prep_beh(const float* __restrict__ cb,
                                                _Float16* __restrict__ Bq,
                                                float* __restrict__ esq) {
    int wave = threadIdx.x >> 6, lane = threadIdx.x & 63;
    int row = blockIdx.x * 4 + wave;                 // grid = 2048
    f4v v = *(const f4v*)(cb + (size_t)row * K_DIM + lane * 4);
    h4v h;
    float sq = 0.f;
    #pragma unroll
    for (int j = 0; j < 4; ++j) {
        h[j] = (_Float16)v[j];
        sq += v[j] * v[j];
    }
    *(h4v*)&Bq[(size_t)row * K_DIM + lane * 4] = h;
    #pragma unroll
    for (int m = 32; m; m >>= 1) sq += __shfl_xor(sq, m);
    if (lane == 0) esq[row] = sq;
}

// ---------------- coarse GEMM + fused 2-min argmin --------------------------
// key = esq - 2*(zh.eh)   (zsq dropped: row-constant)
__global__ __launch_bounds__(256) void coarse_gemm(
        const _Float16* __restrict__ Aq, const _Float16* __restrict__ Bq,
        const float* __restrict__ esq, ulonglong2* __restrict__ slices) {
    __shared__ __align__(16) _Float16 As[BM * BKT];  // 8 KB
    __shared__ __align__(16) _Float16 Bs[BN * BKT];  // 8 KB
    __shared__ ulonglong2 red[BM][2];                // 4 KB

    int bid = blockIdx.x;
    int bm = (bid / GN) % (M_ROWS / BM);
    int bn = (bid / (GN * (M_ROWS / BM))) * GN + (bid % GN);
    int m0 = bm * BM, n0 = bn * BN;

    int t = threadIdx.x;
    int lane = t & 63, wave = t >> 6;
    int quad = lane >> 4, l15 = lane & 15;
    int wm = (wave & 1) * 64, wn = (wave >> 1) * 64;

    f32x4 acc[4][4] = {};

    const _Float16* Ag = Aq + (size_t)m0 * K_DIM;
    const _Float16* Bg = Bq + (size_t)n0 * K_DIM;

    // stage 128 rows x 32 f16 (4x16B chunks per 64B row), stride 256 f16
    auto stage = [&](const _Float16* gbase, _Float16* lds) {
        #pragma unroll
        for (int i = 0; i < 2; ++i) {
            int c = t + i * 256;                     // chunk id 0..511
            int row = c >> 2, seg = c & 3;
            const _Float16* gp = gbase + (size_t)row * K_DIM + seg * 8;
            __builtin_amdgcn_global_load_lds((gbl_cvoid*)gp,
                                             (lds_void*)(lds + (size_t)c * 8),
                                             16, 0, 0);
        }
    };

    auto compute = [&]() {
        half8 af[4], bf[4];
        #pragma unroll
        for (int i = 0; i < 4; ++i) {
            af[i] = *(const half8*)&As[(wm + i * 16 + l15) * BKT + quad * 8];
            bf[i] = *(const half8*)&Bs[(wn + i * 16 + l15) * BKT + quad * 8];
        }
        #pragma unroll
        for (int mi = 0; mi < 4; ++mi)
            #pragma unroll
            for (int ni = 0; ni < 4; ++ni)
                acc[mi][ni] = __builtin_amdgcn_mfma_f32_16x16x32_f16(
                    af[mi], bf[ni], acc[mi][ni], 0, 0, 0);
    };

    #pragma unroll 1
    for (int kt = 0; kt < 8; ++kt) {
        __syncthreads();
        stage(Ag + kt * BKT, As);
        stage(Bg + kt * BKT, Bs);
        __syncthreads();
        compute();
    }

    // Epilogue: 2-smallest of key = fmaf(-2, acc, esq) per row over this slice
    float es[4];
    #pragma unroll
    for (int ni = 0; ni < 4; ++ni)
        es[ni] = esq[n0 + wn + ni * 16 + l15];

    #pragma unroll
    for (int mi = 0; mi < 4; ++mi) {
        #pragma unroll
        for (int r = 0; r < 4; ++r) {
            unsigned long long b1 = ~0ULL, b2 = ~0ULL;
            #pragma unroll
            for (int ni = 0; ni < 4; ++ni) {
                unsigned gCol = (unsigned)(n0 + wn + ni * 16 + l15);
                float key = fmaf(-2.0f, acc[mi][ni][r], es[ni]);
                unsigned long long p = pack_key(key, gCol);
                if (p < b1) { b2 = b1; b1 = p; }
                else if (p < b2) b2 = p;
            }
            #pragma unroll
            for (int m = 1; m < 16; m <<= 1) {
                unsigned long long o1 =
                    (unsigned long long)__shfl_xor((long long)b1, m);
                unsigned long long o2 =
                    (unsigned long long)__shfl_xor((long long)b2, m);
                merge2(b1, b2, o1, o2);
            }
            if (l15 == 0) {
                int rowl = wm + mi * 16 + quad * 4 + r;
                red[rowl][wave >> 1] = make_ulonglong2(b1, b2);
            }
        }
    }
    __syncthreads();
    if (t < BM) {
        ulonglong2 a = red[t][0], b = red[t][1];
        unsigned long long b1 = a.x, b2 = a.y;
        merge2(b1, b2, b.x, b.y);
        slices[(size_t)(m0 + t) * NSLICE + bn] = make_ulonglong2(b1, b2);
    }
}

// ---------------- merge slices -> bestidx + flag + compacted list -----------
__global__ __launch_bounds__(256) void merge_slices(
        const ulonglong2* __restrict__ slices,
        int* __restrict__ bestidx, int* __restrict__ flags,
        int* __restrict__ list, int* __restrict__ count) {
    int wave = threadIdx.x >> 6, lane = threadIdx.x & 63;
    int row = blockIdx.x * 4 + wave;                 // grid = 8192
    ulonglong2 p = slices[(size_t)row * NSLICE + lane];
    unsigned long long b1 = p.x, b2 = p.y;
    #pragma unroll
    for (int m = 1; m < 64; m <<= 1) {
        unsigned long long o1 = (unsigned long long)__shfl_xor((long long)b1, m);
        unsigned long long o2 = (unsigned long long)__shfl_xor((long long)b2, m);
        merge2(b1, b2, o1, o2);
    }
    if (lane == 0) {
        bestidx[row] = (int)(unsigned)(b1 & 0xFFFFFFFFULL);
        int f = (unpack_key(b2) - unpack_key(b1) <= MARGIN) ? 1 : 0;
        flags[row] = f;
        if (f) { int pos = atomicAdd(count, 1); list[pos] = row; }
    }
}

// ---------------- refine: exact fp64 over candidate set only ----------------
// One row per active block (grid-stride over compacted list). Candidates:
//   slice top-1 if within margin of global b1; full 128-code slice if slice
//   top-2 within margin (covers codes hidden below the stored top-2).
__global__ __launch_bounds__(256) void refine(
        const float* __restrict__ z, const float* __restrict__ cb,
        const ulonglong2* __restrict__ slices,
        const int* __restrict__ list, const int* __restrict__ count,
        int* __restrict__ bestidx) {
    __shared__ float zrow[K_DIM];
    __shared__ int cand[MAXCAND];
    __shared__ int ncand_s;
    __shared__ unsigned long long sb1;
    __shared__ double wd[4];
    __shared__ int wc[4];
    int t = threadIdx.x, lane = t & 63, wave = t >> 6;
    int n = *count;
    #pragma unroll 1
    for (int li = blockIdx.x; li < n; li += 2048) {
        int row = list[li];
        __syncthreads();                             // protect shared reuse
        zrow[t] = z[(size_t)row * K_DIM + t];
        if (t == 0) ncand_s = 0;
        __syncthreads();
        ulonglong2 p = make_ulonglong2(~0ULL, ~0ULL);
        if (wave == 0) {
            p = slices[(size_t)row * NSLICE + lane];
            unsigned long long b1 = p.x;
            #pragma unroll
            for (int m = 1; m < 64; m <<= 1) {
                unsigned long long o =
                    (unsigned long long)__shfl_xor((long long)b1, m);
                b1 = o < b1 ? o : b1;
            }
            if (lane == 0) sb1 = b1;
        }
        __syncthreads();
        float thr = unpack_key(sb1) + MARGIN;
        if (wave == 0) {
            float k1 = unpack_key(p.x), k2 = unpack_key(p.y);
            if (k2 <= thr) {                         // hidden codes possible
                int pos = atomicAdd(&ncand_s, 128);
                if (pos + 128 <= MAXCAND)
                    for (int j = 0; j < 128; ++j) cand[pos + j] = lane * 128 + j;
            } else if (k1 <= thr) {
                int pos = atomicAdd(&ncand_s, 1);
                if (pos < MAXCAND) cand[pos] = (int)(unsigned)(p.x & 0xFFFFFFFFULL);
            }
        }
        __syncthreads();
        int nc = ncand_s;
        bool full = nc > MAXCAND;                    // rigorous fallback
        int total = full ? N_CODES : nc;
        double bd = 1e300;
        int bc = 0x7fffffff;
        #pragma unroll 1
        for (int base = 0; base < total; base += 256) {
            int i = base + t;
            if (i < total) {
                int code = full ? i : cand[i];
                const f4v* e4 = (const f4v*)(cb + (size_t)code * K_DIM);
                double s0 = 0, s1 = 0, s2 = 0, s3 = 0;
                #pragma unroll 4
                for (int k4 = 0; k4 < 64; ++k4) {
                    f4v e = e4[k4];
                    f4v zz = *(const f4v*)&zrow[k4 * 4];
                    float d0 = zz[0] - e[0], d1 = zz[1] - e[1];
                    float d2 = zz[2] - e[2], d3 = zz[3] - e[3];
                    s0 = fma((double)d0, (double)d0, s0);
                    s1 = fma((double)d1, (double)d1, s1);
                    s2 = fma((double)d2, (double)d2, s2);
                    s3 = fma((double)d3, (double)d3, s3);
                }
                double s = (s0 + s1) + (s2 + s3);
                if (s < bd || (s == bd && code < bc)) { bd = s; bc = code; }
            }
        }
        #pragma unroll
        for (int m = 1; m < 64; m <<= 1) {
            double od = __shfl_xor(bd, m);
            int oc = __shfl_xor(bc, m);
            if (od < bd || (od == bd && oc < bc)) { bd = od; bc = oc; }
        }
        if (lane == 0) { wd[wave] = bd; wc[wave] = bc; }
        __syncthreads();
        if (t == 0) {
            #pragma unroll
            for (int w = 1; w < 4; ++w)
                if (wd[w] < bd || (wd[w] == bd && wc[w] < bc)) { bd = wd[w]; bc = wc[w]; }
            bestidx[row] = bc;
        }
    }
}

// ---------------- ws-light fallback (only if ws too small) ------------------
__global__ __launch_bounds__(256) void vq_bruteforce(const float* __restrict__ z,
                                                     const float* __restrict__ cb,
                                                     float* __restrict__ out_idx) {
    __shared__ float As[128 * 16];
    __shared__ float Bs[128 * 16];
    int t = threadIdx.x;
    int tx = t & 15, ty = t >> 4;
    int r0 = blockIdx.x * 128;
    unsigned long long best[8];
    #pragma unroll
    for (int j = 0; j < 8; ++j) best[j] = ~0ULL;

    for (int n0 = 0; n0 < N_CODES; n0 += 128) {
        float acc[8][8] = {};
        for (int k0 = 0; k0 < K_DIM; k0 += 16) {
            __syncthreads();
            int row = t >> 1, c8 = (t & 1) * 8;
            #pragma unroll
            for (int j = 0; j < 8; ++j)
                As[row * 16 + c8 + j] = z[(size_t)(r0 + row) * K_DIM + k0 + c8 + j];
            #pragma unroll
            for (int j = 0; j < 8; ++j)
                Bs[row * 16 + c8 + j] = cb[(size_t)(n0 + row) * K_DIM + k0 + c8 + j];
            __syncthreads();
            #pragma unroll
            for (int k = 0; k < 16; ++k) {
                float a[8], b[8];
                #pragma unroll
                for (int j = 0; j < 8; ++j) a[j] = As[(ty * 8 + j) * 16 + k];
                #pragma unroll
                for (int j = 0; j < 8; ++j) b[j] = Bs[(tx * 8 + j) * 16 + k];
                #pragma unroll
                for (int i = 0; i < 8; ++i)
                    #pragma unroll
                    for (int j = 0; j < 8; ++j) {
                        float d = a[i] - b[j];
                        acc[i][j] += d * d;
                    }
            }
        }
        #pragma unroll
        for (int i = 0; i < 8; ++i) {
            unsigned long long bv = ~0ULL;
            #pragma unroll
            for (int j = 0; j < 8; ++j) {
                unsigned long long p =
                    pack_key(acc[i][j], (unsigned)(n0 + tx * 8 + j));
                bv = (p < bv) ? p : bv;
            }
            #pragma unroll
            for (int m = 1; m < 16; m <<= 1) {
                unsigned long long o =
                    (unsigned long long)__shfl_xor((long long)bv, m);
                bv = (o < bv) ? o : bv;
            }
            if (tx == 0 && bv < best[i]) best[i] = bv;
        }
    }
    if (tx == 0) {
        #pragma unroll
        for (int i = 0; i < 8; ++i)
            out_idx[r0 + ty * 8 + i] =
                (float)(unsigned)(best[i] & 0xFFFFFFFFULL);
    }
}

// ---------------- finalize: gather, straight-through out, loss sum ----------
__global__ __launch_bounds__(256) void finalize(const float* __restrict__ z,
                                                const float* __restrict__ cb,
                                                const int* __restrict__ bestidx,
                                                float* __restrict__ out,
                                                double* __restrict__ accum,
                                                int use_int) {
    int wave = threadIdx.x >> 6, lane = threadIdx.x & 63;
    float* out_idx = out + (size_t)M_ROWS * K_DIM;
    float se = 0.f;
    #pragma unroll 1
    for (int row = blockIdx.x * 4 + wave; row < M_ROWS; row += 1024 * 4) {
        int idx = use_int ? bestidx[row] : (int)out_idx[row];
        f4v zv = *(const f4v*)(z  + (size_t)row * K_DIM + lane * 4);
        f4v qv = *(const f4v*)(cb + (size_t)idx * K_DIM + lane * 4);
        f4v ov;
        #pragma unroll
        for (int j = 0; j < 4; ++j) {
            float d = qv[j] - zv[j];                 // ref: z_q - z_e
            ov[j] = zv[j] + d;                       // ref: z_e + (z_q - z_e)
            se += d * d;
        }
        *(f4v*)(out + (size_t)row * K_DIM + lane * 4) = ov;
        if (lane == 0) out_idx[row] = (float)idx;
    }
    #pragma unroll
    for (int m = 32; m; m >>= 1) se += __shfl_xor(se, m);
    __shared__ float part[4];
    if (lane == 0) part[wave] = se;
    __syncthreads();
    if (threadIdx.x == 0)
        atomicAdd(accum, (double)((part[0] + part[1]) + (part[2] + part[3])));
}

__global__ void write_loss(const double* __restrict__ accum,
                           float* __restrict__ out) {
    // vq_loss = codebook_loss + 0.25*commitment_loss = 1.25 * mean(diff^2)
    out[(size_t)M_ROWS * K_DIM + M_ROWS] =
        (float)(1.25 * (*accum / (double)((size_t)M_ROWS * K_DIM)));
}

// ---------------- launch ----------------------------------------------------
extern "C" void kernel_launch(void* const* d_in, const int* in_sizes, int n_in,
                              void* d_out, int out_size, void* d_ws, size_t ws_size,
                              hipStream_t stream) {
    const float* z  = (const float*)d_in[0];
    const float* cb = (const float*)d_in[1];
    float* out = (float*)d_out;
    float* out_idx = out + (size_t)M_ROWS * K_DIM;

    size_t offA  = 0;                                             // Aq 16 MB
    size_t offBq = offA + (size_t)M_ROWS * K_DIM * 2;             // Bq 4 MB
    size_t offE  = offBq + (size_t)N_CODES * K_DIM * 2;           // esq 32 KB
    size_t offS  = offE + (size_t)N_CODES * 4;                    // slices 32 MB
    size_t offBI = offS + (size_t)M_ROWS * NSLICE * 16;           // bestidx 128 KB
    size_t offF  = offBI + (size_t)M_ROWS * 4;                    // flags 128 KB
    size_t offL  = offF + (size_t)M_ROWS * 4;                     // list 128 KB
    size_t offC  = offL + (size_t)M_ROWS * 4;                     // count 16 B
    size_t offAcc = offC + 16;
    size_t need  = offAcc + 16;

    if (ws_size >= need) {
        _Float16* Aq = (_Float16*)((char*)d_ws + offA);
        _Float16* Bq = (_Float16*)((char*)d_ws + offBq);
        float* esq   = (float*)((char*)d_ws + offE);
        ulonglong2* slices = (ulonglong2*)((char*)d_ws + offS);
        int* bestidx = (int*)((char*)d_ws + offBI);
        int* flags   = (int*)((char*)d_ws + offF);
        int* list    = (int*)((char*)d_ws + offL);
        int* count   = (int*)((char*)d_ws + offC);
        double* accum = (double*)((char*)d_ws + offAcc);

        hipMemsetAsync((char*)d_ws + offC, 0, 32, stream);        // count+accum

        prep_zh<<<1024, 256, 0, stream>>>(z, Aq);
        prep_beh<<<N_CODES / 4, 256, 0, stream>>>(cb, Bq, esq);
        coarse_gemm<<<(M_ROWS / BM) * (N_CODES / BN), 256, 0, stream>>>(
            Aq, Bq, esq, slices);
        merge_slices<<<M_ROWS / 4, 256, 0, stream>>>(slices, bestidx, flags,
                                                     list, count);
        refine<<<2048, 256, 0, stream>>>(z, cb, slices, list, count, bestidx);
        finalize<<<1024, 256, 0, stream>>>(z, cb, bestidx, out, accum, 1);
        write_loss<<<1, 1, 0, stream>>>(accum, out);
    } else {
        double* accum = (double*)d_ws;
        hipMemsetAsync(d_ws, 0, sizeof(double), stream);
        vq_bruteforce<<<M_ROWS / 128, 256, 0, stream>>>(z, cb, out_idx);
        finalize<<<1024, 256, 0, stream>>>(z, cb, nullptr, out, accum, 0);
        write_loss<<<1, 1, 0, stream>>>(accum, out);
    }
}

// Round 7
// 453.682 us; speedup vs baseline: 3.6208x; 1.0524x over previous
//
#include <hip/hip_runtime.h>
#include <hip/hip_bf16.h>
#include <stdint.h>

// Problem constants
#define M_ROWS 32768
#define N_CODES 8192
#define K_DIM 256
#define NSLICE 64            // N_CODES / BN
#define MARGIN 0.25f         // coarse-key uncertainty window, ~40 sigma
#define MAXCAND 1280

// Coarse GEMM tile config (proven 128x128 skeleton; K staged as 4x(2x32))
#define BM 128
#define BN 128
#define GN 8                 // N-blocks per swizzle panel (L2 locality)

typedef _Float16 half8 __attribute__((ext_vector_type(8)));
typedef _Float16 h4v __attribute__((ext_vector_type(4)));
typedef float f4v __attribute__((ext_vector_type(4)));
typedef float f32x4 __attribute__((ext_vector_type(4)));
typedef __attribute__((address_space(3))) void lds_void;
typedef const __attribute__((address_space(1))) void gbl_cvoid;

// Monotone map: fp32 bits -> uint32 preserving < order (handles sign)
__device__ __forceinline__ unsigned mono32(float f) {
    unsigned u = __float_as_uint(f);
    return (u & 0x80000000u) ? ~u : (u | 0x80000000u);
}
__device__ __forceinline__ unsigned long long pack_key(float d, unsigned col) {
    return ((unsigned long long)mono32(d) << 32) | (unsigned long long)col;
}
__device__ __forceinline__ float unpack_key(unsigned long long k) {
    unsigned m = (unsigned)(k >> 32);
    unsigned u = (m & 0x80000000u) ? (m & 0x7fffffffu) : ~m;
    return __uint_as_float(u);
}
// 2-min pair merge: (b1,b2) <- two smallest of {b1,b2,o1,o2}
__device__ __forceinline__ void merge2(unsigned long long& b1, unsigned long long& b2,
                                       unsigned long long o1, unsigned long long o2) {
    unsigned long long n1 = b1 < o1 ? b1 : o1;
    unsigned long long hi = b1 < o1 ? o1 : b1;
    unsigned long long l2 = b2 < o2 ? b2 : o2;
    b2 = hi < l2 ? hi : l2;
    b1 = n1;
}

// ---------------- prep: z -> f16 (elementwise, grid-stride) -----------------
__global__ __launch_bounds__(256) void prep_zh(const float* __restrict__ z,
                                               _Float16* __restrict__ Aq) {
    int tid = blockIdx.x * 256 + threadIdx.x;
    const f4v* z4 = (const f4v*)z;
    #pragma unroll 1
    for (int i = tid; i < M_ROWS * (K_DIM / 4); i += 1024 * 256) {
        f4v v = z4[i];
        h4v h;
        #pragma unroll
        for (int j = 0; j < 4; ++j) h[j] = (_Float16)v[j];
        *(h4v*)&Aq[(size_t)i * 4] = h;
    }
}

// ---------------- prep: codebook -> f16 + esq (fp32) ------------------------
__global__ __launch_bounds__(256) void prep_beh(const float* __restrict__ cb,
                                                _Float16* __restrict__ Bq,
                                                float* __restrict__ esq) {
    int wave = threadIdx.x >> 6, lane = threadIdx.x & 63;
    int row = blockIdx.x * 4 + wave;                 // grid = 2048
    f4v v = *(const f4v*)(cb + (size_t)row * K_DIM + lane * 4);
    h4v h;
    float sq = 0.f;
    #pragma unroll
    for (int j = 0; j < 4; ++j) {
        h[j] = (_Float16)v[j];
        sq += v[j] * v[j];
    }
    *(h4v*)&Bq[(size_t)row * K_DIM + lane * 4] = h;
    #pragma unroll
    for (int m = 32; m; m >>= 1) sq += __shfl_xor(sq, m);
    if (lane == 0) esq[row] = sq;
}

// ---------------- coarse GEMM + fused 2-min argmin --------------------------
// key = esq - 2*(zh.eh)   (zsq dropped: row-constant)
__global__ __launch_bounds__(256) void coarse_gemm(
        const _Float16* __restrict__ Aq, const _Float16* __restrict__ Bq,
        const float* __restrict__ esq, ulonglong2* __restrict__ slices) {
    __shared__ __align__(16) char smem[32768];       // 4x8KB chunk tiles
    _Float16* As0 = (_Float16*)smem;
    _Float16* As1 = (_Float16*)(smem + 8192);
    _Float16* Bs0 = (_Float16*)(smem + 16384);
    _Float16* Bs1 = (_Float16*)(smem + 24576);
    ulonglong2 (*red)[2] = (ulonglong2(*)[2])smem;   // 4KB alias (post-barrier)

    int bid = blockIdx.x;
    int bm = (bid / GN) % (M_ROWS / BM);
    int bn = (bid / (GN * (M_ROWS / BM))) * GN + (bid % GN);
    int m0 = bm * BM, n0 = bn * BN;

    int t = threadIdx.x;
    int lane = t & 63, wave = t >> 6;
    int quad = lane >> 4, l15 = lane & 15;
    int wm = (wave & 1) * 64, wn = (wave >> 1) * 64;

    f32x4 acc[4][4] = {};

    // per-thread global staging pointers: row = t>>2 (+64), seg = t&3
    const _Float16* pA = Aq + (size_t)(m0 + (t >> 2)) * K_DIM + (t & 3) * 8;
    const _Float16* pB = Bq + (size_t)(n0 + (t >> 2)) * K_DIM + (t & 3) * 8;
    const size_t rstep = (size_t)64 * K_DIM;

    auto compute = [&](const _Float16* A, const _Float16* B) {
        half8 af[4], bf[4];
        #pragma unroll
        for (int i = 0; i < 4; ++i) {
            af[i] = *(const half8*)&A[(wm + i * 16 + l15) * 32 + quad * 8];
            bf[i] = *(const half8*)&B[(wn + i * 16 + l15) * 32 + quad * 8];
        }
        #pragma unroll
        for (int mi = 0; mi < 4; ++mi)
            #pragma unroll
            for (int ni = 0; ni < 4; ++ni)
                acc[mi][ni] = __builtin_amdgcn_mfma_f32_16x16x32_f16(
                    af[mi], bf[ni], acc[mi][ni], 0, 0, 0);
    };

    // K loop: 4 barrier-pairs, 2x32-K chunks per pair (same K order as before)
    #pragma unroll 1
    for (int kp = 0; kp < 4; ++kp) {
        int ko = kp * 64;
        __syncthreads();
        __builtin_amdgcn_global_load_lds((gbl_cvoid*)(pA + ko),
                                         (lds_void*)(As0 + t * 8), 16, 0, 0);
        __builtin_amdgcn_global_load_lds((gbl_cvoid*)(pA + rstep + ko),
                                         (lds_void*)(As0 + t * 8 + 2048), 16, 0, 0);
        __builtin_amdgcn_global_load_lds((gbl_cvoid*)(pA + ko + 32),
                                         (lds_void*)(As1 + t * 8), 16, 0, 0);
        __builtin_amdgcn_global_load_lds((gbl_cvoid*)(pA + rstep + ko + 32),
                                         (lds_void*)(As1 + t * 8 + 2048), 16, 0, 0);
        __builtin_amdgcn_global_load_lds((gbl_cvoid*)(pB + ko),
                                         (lds_void*)(Bs0 + t * 8), 16, 0, 0);
        __builtin_amdgcn_global_load_lds((gbl_cvoid*)(pB + rstep + ko),
                                         (lds_void*)(Bs0 + t * 8 + 2048), 16, 0, 0);
        __builtin_amdgcn_global_load_lds((gbl_cvoid*)(pB + ko + 32),
                                         (lds_void*)(Bs1 + t * 8), 16, 0, 0);
        __builtin_amdgcn_global_load_lds((gbl_cvoid*)(pB + rstep + ko + 32),
                                         (lds_void*)(Bs1 + t * 8 + 2048), 16, 0, 0);
        __syncthreads();
        compute(As0, Bs0);
        compute(As1, Bs1);
    }

    // Epilogue: float 2-min per lane, light (b1:u64, k2:u32) shuffle reduce
    float es[4];
    #pragma unroll
    for (int ni = 0; ni < 4; ++ni)
        es[ni] = esq[n0 + wn + ni * 16 + l15];
    __syncthreads();                                 // K-reads done; red aliases

    #pragma unroll
    for (int mi = 0; mi < 4; ++mi) {
        #pragma unroll
        for (int r = 0; r < 4; ++r) {
            float f1 = 3.4e38f, f2 = 3.4e38f;
            unsigned c1 = 0;
            #pragma unroll
            for (int ni = 0; ni < 4; ++ni) {
                float key = fmaf(-2.0f, acc[mi][ni][r], es[ni]);
                bool lt1 = key < f1;
                float t2 = key < f2 ? key : f2;
                f2 = lt1 ? f1 : t2;
                c1 = lt1 ? (unsigned)(n0 + wn + ni * 16 + l15) : c1;
                f1 = lt1 ? key : f1;
            }
            unsigned long long b1 = pack_key(f1, c1);
            unsigned k2 = mono32(f2);
            #pragma unroll
            for (int m = 1; m < 16; m <<= 1) {
                unsigned long long o1 =
                    (unsigned long long)__shfl_xor((long long)b1, m);
                unsigned ok = (unsigned)__shfl_xor((int)k2, m);
                unsigned hi = (unsigned)((b1 < o1 ? o1 : b1) >> 32);
                b1 = b1 < o1 ? b1 : o1;
                unsigned mn = k2 < ok ? k2 : ok;
                k2 = hi < mn ? hi : mn;
            }
            if (l15 == 0) {
                int rowl = wm + mi * 16 + quad * 4 + r;
                red[rowl][wave >> 1] = make_ulonglong2(
                    b1, ((unsigned long long)k2 << 32) | 0xFFFFFFFFULL);
            }
        }
    }
    __syncthreads();
    if (t < BM) {
        ulonglong2 a = red[t][0], b = red[t][1];
        unsigned long long b1 = a.x < b.x ? a.x : b.x;
        unsigned hi = (unsigned)((a.x < b.x ? b.x : a.x) >> 32);
        unsigned ka = (unsigned)(a.y >> 32), kb = (unsigned)(b.y >> 32);
        unsigned mn = ka < kb ? ka : kb;
        unsigned k2 = hi < mn ? hi : mn;
        slices[(size_t)(m0 + t) * NSLICE + bn] = make_ulonglong2(
            b1, ((unsigned long long)k2 << 32) | 0xFFFFFFFFULL);
    }
}

// ---------------- merge slices -> bestidx + flag + compacted list -----------
__global__ __launch_bounds__(256) void merge_slices(
        const ulonglong2* __restrict__ slices,
        int* __restrict__ bestidx, int* __restrict__ flags,
        int* __restrict__ list, int* __restrict__ count) {
    int wave = threadIdx.x >> 6, lane = threadIdx.x & 63;
    int row = blockIdx.x * 4 + wave;                 // grid = 8192
    ulonglong2 p = slices[(size_t)row * NSLICE + lane];
    unsigned long long b1 = p.x, b2 = p.y;
    #pragma unroll
    for (int m = 1; m < 64; m <<= 1) {
        unsigned long long o1 = (unsigned long long)__shfl_xor((long long)b1, m);
        unsigned long long o2 = (unsigned long long)__shfl_xor((long long)b2, m);
        merge2(b1, b2, o1, o2);
    }
    if (lane == 0) {
        bestidx[row] = (int)(unsigned)(b1 & 0xFFFFFFFFULL);
        int f = (unpack_key(b2) - unpack_key(b1) <= MARGIN) ? 1 : 0;
        flags[row] = f;
        if (f) { int pos = atomicAdd(count, 1); list[pos] = row; }
    }
}

// ---------------- refine: exact fp64 over candidate set only ----------------
__global__ __launch_bounds__(256) void refine(
        const float* __restrict__ z, const float* __restrict__ cb,
        const ulonglong2* __restrict__ slices,
        const int* __restrict__ list, const int* __restrict__ count,
        int* __restrict__ bestidx) {
    __shared__ float zrow[K_DIM];
    __shared__ int cand[MAXCAND];
    __shared__ int ncand_s;
    __shared__ unsigned long long sb1;
    __shared__ double wd[4];
    __shared__ int wc[4];
    int t = threadIdx.x, lane = t & 63, wave = t >> 6;
    int n = *count;
    #pragma unroll 1
    for (int li = blockIdx.x; li < n; li += 2048) {
        int row = list[li];
        __syncthreads();                             // protect shared reuse
        zrow[t] = z[(size_t)row * K_DIM + t];
        if (t == 0) ncand_s = 0;
        __syncthreads();
        ulonglong2 p = make_ulonglong2(~0ULL, ~0ULL);
        if (wave == 0) {
            p = slices[(size_t)row * NSLICE + lane];
            unsigned long long b1 = p.x;
            #pragma unroll
            for (int m = 1; m < 64; m <<= 1) {
                unsigned long long o =
                    (unsigned long long)__shfl_xor((long long)b1, m);
                b1 = o < b1 ? o : b1;
            }
            if (lane == 0) sb1 = b1;
        }
        __syncthreads();
        float thr = unpack_key(sb1) + MARGIN;
        if (wave == 0) {
            float k1 = unpack_key(p.x), k2 = unpack_key(p.y);
            if (k2 <= thr) {                         // hidden codes possible
                int pos = atomicAdd(&ncand_s, 128);
                if (pos + 128 <= MAXCAND)
                    for (int j = 0; j < 128; ++j) cand[pos + j] = lane * 128 + j;
            } else if (k1 <= thr) {
                int pos = atomicAdd(&ncand_s, 1);
                if (pos < MAXCAND) cand[pos] = (int)(unsigned)(p.x & 0xFFFFFFFFULL);
            }
        }
        __syncthreads();
        int nc = ncand_s;
        bool full = nc > MAXCAND;                    // rigorous fallback
        int total = full ? N_CODES : nc;
        double bd = 1e300;
        int bc = 0x7fffffff;
        #pragma unroll 1
        for (int base = 0; base < total; base += 256) {
            int i = base + t;
            if (i < total) {
                int code = full ? i : cand[i];
                const f4v* e4 = (const f4v*)(cb + (size_t)code * K_DIM);
                double s0 = 0, s1 = 0, s2 = 0, s3 = 0;
                #pragma unroll 4
                for (int k4 = 0; k4 < 64; ++k4) {
                    f4v e = e4[k4];
                    f4v zz = *(const f4v*)&zrow[k4 * 4];
                    float d0 = zz[0] - e[0], d1 = zz[1] - e[1];
                    float d2 = zz[2] - e[2], d3 = zz[3] - e[3];
                    s0 = fma((double)d0, (double)d0, s0);
                    s1 = fma((double)d1, (double)d1, s1);
                    s2 = fma((double)d2, (double)d2, s2);
                    s3 = fma((double)d3, (double)d3, s3);
                }
                double s = (s0 + s1) + (s2 + s3);
                if (s < bd || (s == bd && code < bc)) { bd = s; bc = code; }
            }
        }
        #pragma unroll
        for (int m = 1; m < 64; m <<= 1) {
            double od = __shfl_xor(bd, m);
            int oc = __shfl_xor(bc, m);
            if (od < bd || (od == bd && oc < bc)) { bd = od; bc = oc; }
        }
        if (lane == 0) { wd[wave] = bd; wc[wave] = bc; }
        __syncthreads();
        if (t == 0) {
            #pragma unroll
            for (int w = 1; w < 4; ++w)
                if (wd[w] < bd || (wd[w] == bd && wc[w] < bc)) { bd = wd[w]; bc = wc[w]; }
            bestidx[row] = bc;
        }
    }
}

// ---------------- ws-light fallback (only if ws too small) ------------------
__global__ __launch_bounds__(256) void vq_bruteforce(const float* __restrict__ z,
                                                     const float* __restrict__ cb,
                                                     float* __restrict__ out_idx) {
    __shared__ float As[128 * 16];
    __shared__ float Bs[128 * 16];
    int t = threadIdx.x;
    int tx = t & 15, ty = t >> 4;
    int r0 = blockIdx.x * 128;
    unsigned long long best[8];
    #pragma unroll
    for (int j = 0; j < 8; ++j) best[j] = ~0ULL;

    for (int n0 = 0; n0 < N_CODES; n0 += 128) {
        float acc[8][8] = {};
        for (int k0 = 0; k0 < K_DIM; k0 += 16) {
            __syncthreads();
            int row = t >> 1, c8 = (t & 1) * 8;
            #pragma unroll
            for (int j = 0; j < 8; ++j)
                As[row * 16 + c8 + j] = z[(size_t)(r0 + row) * K_DIM + k0 + c8 + j];
            #pragma unroll
            for (int j = 0; j < 8; ++j)
                Bs[row * 16 + c8 + j] = cb[(size_t)(n0 + row) * K_DIM + k0 + c8 + j];
            __syncthreads();
            #pragma unroll
            for (int k = 0; k < 16; ++k) {
                float a[8], b[8];
                #pragma unroll
                for (int j = 0; j < 8; ++j) a[j] = As[(ty * 8 + j) * 16 + k];
                #pragma unroll
                for (int j = 0; j < 8; ++j) b[j] = Bs[(tx * 8 + j) * 16 + k];
                #pragma unroll
                for (int i = 0; i < 8; ++i)
                    #pragma unroll
                    for (int j = 0; j < 8; ++j) {
                        float d = a[i] - b[j];
                        acc[i][j] += d * d;
                    }
            }
        }
        #pragma unroll
        for (int i = 0; i < 8; ++i) {
            unsigned long long bv = ~0ULL;
            #pragma unroll
            for (int j = 0; j < 8; ++j) {
                unsigned long long p =
                    pack_key(acc[i][j], (unsigned)(n0 + tx * 8 + j));
                bv = (p < bv) ? p : bv;
            }
            #pragma unroll
            for (int m = 1; m < 16; m <<= 1) {
                unsigned long long o =
                    (unsigned long long)__shfl_xor((long long)bv, m);
                bv = (o < bv) ? o : bv;
            }
            if (tx == 0 && bv < best[i]) best[i] = bv;
        }
    }
    if (tx == 0) {
        #pragma unroll
        for (int i = 0; i < 8; ++i)
            out_idx[r0 + ty * 8 + i] =
                (float)(unsigned)(best[i] & 0xFFFFFFFFULL);
    }
}

// ---------------- finalize: gather, straight-through out, loss sum ----------
__global__ __launch_bounds__(256) void finalize(const float* __restrict__ z,
                                                const float* __restrict__ cb,
                                                const int* __restrict__ bestidx,
                                                float* __restrict__ out,
                                                double* __restrict__ accum,
                                                int use_int) {
    int wave = threadIdx.x >> 6, lane = threadIdx.x & 63;
    float* out_idx = out + (size_t)M_ROWS * K_DIM;
    float se = 0.f;
    #pragma unroll 1
    for (int row = blockIdx.x * 4 + wave; row < M_ROWS; row += 1024 * 4) {
        int idx = use_int ? bestidx[row] : (int)out_idx[row];
        f4v zv = *(const f4v*)(z  + (size_t)row * K_DIM + lane * 4);
        f4v qv = *(const f4v*)(cb + (size_t)idx * K_DIM + lane * 4);
        f4v ov;
        #pragma unroll
        for (int j = 0; j < 4; ++j) {
            float d = qv[j] - zv[j];                 // ref: z_q - z_e
            ov[j] = zv[j] + d;                       // ref: z_e + (z_q - z_e)
            se += d * d;
        }
        *(f4v*)(out + (size_t)row * K_DIM + lane * 4) = ov;
        if (lane == 0) out_idx[row] = (float)idx;
    }
    #pragma unroll
    for (int m = 32; m; m >>= 1) se += __shfl_xor(se, m);
    __shared__ float part[4];
    if (lane == 0) part[wave] = se;
    __syncthreads();
    if (threadIdx.x == 0)
        atomicAdd(accum, (double)((part[0] + part[1]) + (part[2] + part[3])));
}

__global__ void write_loss(const double* __restrict__ accum,
                           float* __restrict__ out) {
    // vq_loss = codebook_loss + 0.25*commitment_loss = 1.25 * mean(diff^2)
    out[(size_t)M_ROWS * K_DIM + M_ROWS] =
        (float)(1.25 * (*accum / (double)((size_t)M_ROWS * K_DIM)));
}

// ---------------- launch ----------------------------------------------------
extern "C" void kernel_launch(void* const* d_in, const int* in_sizes, int n_in,
                              void* d_out, int out_size, void* d_ws, size_t ws_size,
                              hipStream_t stream) {
    const float* z  = (const float*)d_in[0];
    const float* cb = (const float*)d_in[1];
    float* out = (float*)d_out;
    float* out_idx = out + (size_t)M_ROWS * K_DIM;

    size_t offA  = 0;                                             // Aq 16 MB
    size_t offBq = offA + (size_t)M_ROWS * K_DIM * 2;             // Bq 4 MB
    size_t offE  = offBq + (size_t)N_CODES * K_DIM * 2;           // esq 32 KB
    size_t offS  = offE + (size_t)N_CODES * 4;                    // slices 32 MB
    size_t offBI = offS + (size_t)M_ROWS * NSLICE * 16;           // bestidx 128 KB
    size_t offF  = offBI + (size_t)M_ROWS * 4;                    // flags 128 KB
    size_t offL  = offF + (size_t)M_ROWS * 4;                     // list 128 KB
    size_t offC  = offL + (size_t)M_ROWS * 4;                     // count 16 B
    size_t offAcc = offC + 16;
    size_t need  = offAcc + 16;

    if (ws_size >= need) {
        _Float16* Aq = (_Float16*)((char*)d_ws + offA);
        _Float16* Bq = (_Float16*)((char*)d_ws + offBq);
        float* esq   = (float*)((char*)d_ws + offE);
        ulonglong2* slices = (ulonglong2*)((char*)d_ws + offS);
        int* bestidx = (int*)((char*)d_ws + offBI);
        int* flags   = (int*)((char*)d_ws + offF);
        int* list    = (int*)((char*)d_ws + offL);
        int* count   = (int*)((char*)d_ws + offC);
        double* accum = (double*)((char*)d_ws + offAcc);

        hipMemsetAsync((char*)d_ws + offC, 0, 32, stream);        // count+accum

        prep_zh<<<1024, 256, 0, stream>>>(z, Aq);
        prep_beh<<<N_CODES / 4, 256, 0, stream>>>(cb, Bq, esq);
        coarse_gemm<<<(M_ROWS / BM) * (N_CODES / BN), 256, 0, stream>>>(
            Aq, Bq, esq, slices);
        merge_slices<<<M_ROWS / 4, 256, 0, stream>>>(slices, bestidx, flags,
                                                     list, count);
        refine<<<2048, 256, 0, stream>>>(z, cb, slices, list, count, bestidx);
        finalize<<<1024, 256, 0, stream>>>(z, cb, bestidx, out, accum, 1);
        write_loss<<<1, 1, 0, stream>>>(accum, out);
    } else {
        double* accum = (double*)d_ws;
        hipMemsetAsync(d_ws, 0, sizeof(double), stream);
        vq_bruteforce<<<M_ROWS / 128, 256, 0, stream>>>(z, cb, out_idx);
        finalize<<<1024, 256, 0, stream>>>(z, cb, nullptr, out, accum, 0);
        write_loss<<<1, 1, 0, stream>>>(accum, out);
    }
}